// Round 4
// baseline (423.465 us; speedup 1.0000x reference)
//
#include <hip/hip_runtime.h>
#include <hip/hip_bf16.h>

#define B_    2
#define T_    2048
#define C_    2048
#define NH_   16
#define KVH_  4
#define HD_   128
#define QKV_  3072
#define M_    4096

typedef float  floatx4 __attribute__((ext_vector_type(4)));
typedef __bf16 bf16x8  __attribute__((ext_vector_type(8)));
typedef __bf16 bf16x4  __attribute__((ext_vector_type(4)));
typedef __bf16 bf16x2  __attribute__((ext_vector_type(2)));

typedef const __attribute__((address_space(1))) void* gas_t;
typedef __attribute__((address_space(3))) void*       las_t;
__device__ __forceinline__ void gl_lds16(const void* g, void* l) {
  __builtin_amdgcn_global_load_lds((gas_t)g, (las_t)l, 16, 0, 0);
}

__device__ __forceinline__ int pack2(float a, float b) {
  bf16x2 t = { (__bf16)a, (__bf16)b };
  return __builtin_bit_cast(int, t);
}

// ---------------- fp32 -> bf16 conversion (memory-bound) ----------------
__global__ __launch_bounds__(256) void cvt_bf16(const float* __restrict__ src,
                                                __bf16* __restrict__ dst, int n4) {
  int i = blockIdx.x * blockDim.x + threadIdx.x;
  if (i < n4) {
    float4 f = ((const float4*)src)[i];
    bf16x4 o = { (__bf16)f.x, (__bf16)f.y, (__bf16)f.z, (__bf16)f.w };
    ((bf16x4*)dst)[i] = o;
  }
}

// ---------------- C = A[M][K] * B[N][K]^T, fp32 out (m97 structure) ----------------
__global__ __launch_bounds__(256) void gemm_bt(const __bf16* __restrict__ A,
                                               const __bf16* __restrict__ Bm,
                                               float* __restrict__ Cc,
                                               int N, int K) {
  __shared__ __align__(16) __bf16 As[128 * 32];
  __shared__ __align__(16) __bf16 Bs[128 * 32];
  const int tid  = threadIdx.x;
  const int wid  = tid >> 6, lane = tid & 63, quad = lane >> 4, r16 = lane & 15;
  const int bm   = blockIdx.y * 128, bn = blockIdx.x * 128;
  const int wm   = (wid >> 1) * 64, wn = (wid & 1) * 64;
  const int srow = wid * 16 + (lane >> 2);
  const int scol = (lane & 3) * 8;
  const __bf16* aptr = A  + (size_t)(bm + srow) * K + scol;
  const __bf16* bptr = Bm + (size_t)(bn + srow) * K + scol;
  __bf16* ldsA0 = &As[wid * 512];
  __bf16* ldsA1 = &As[2048 + wid * 512];
  __bf16* ldsB0 = &Bs[wid * 512];
  __bf16* ldsB1 = &Bs[2048 + wid * 512];
  const size_t rowskip = (size_t)64 * K;

  floatx4 acc[4][4];
  #pragma unroll
  for (int i = 0; i < 4; i++)
    #pragma unroll
    for (int j = 0; j < 4; j++) acc[i][j] = (floatx4){0.f, 0.f, 0.f, 0.f};

  for (int k0 = 0; k0 < K; k0 += 32) {
    gl_lds16(aptr + k0,           ldsA0);
    gl_lds16(aptr + rowskip + k0, ldsA1);
    gl_lds16(bptr + k0,           ldsB0);
    gl_lds16(bptr + rowskip + k0, ldsB1);
    __syncthreads();

    bf16x8 af[4], bfr[4];
    #pragma unroll
    for (int i = 0; i < 4; i++) af[i]  = *(const bf16x8*)&As[(wm + i * 16 + r16) * 32 + quad * 8];
    #pragma unroll
    for (int j = 0; j < 4; j++) bfr[j] = *(const bf16x8*)&Bs[(wn + j * 16 + r16) * 32 + quad * 8];

    #pragma unroll
    for (int i = 0; i < 4; i++)
      #pragma unroll
      for (int j = 0; j < 4; j++)
        acc[i][j] = __builtin_amdgcn_mfma_f32_16x16x32_bf16(af[i], bfr[j], acc[i][j], 0, 0, 0);
    __syncthreads();
  }

  #pragma unroll
  for (int i = 0; i < 4; i++) {
    #pragma unroll
    for (int reg = 0; reg < 4; reg++) {
      int row = bm + wm + i * 16 + quad * 4 + reg;
      float* crow = Cc + (size_t)row * N + bn + wn;
      #pragma unroll
      for (int j = 0; j < 4; j++) crow[j * 16 + r16] = acc[i][j][reg];
    }
  }
}

// ---------------- RoPE + RMSNorm, one wave per (b,t) row ----------------
__global__ __launch_bounds__(256) void rope_norm(const float* __restrict__ qkv,
                                                 const float* __restrict__ qw,
                                                 const float* __restrict__ kw,
                                                 const float* __restrict__ fc,
                                                 const float* __restrict__ fs,
                                                 __bf16* __restrict__ qn,
                                                 __bf16* __restrict__ kn) {
  const int tid  = threadIdx.x;
  const int wid  = tid >> 6, lane = tid & 63;
  const int row  = blockIdx.x * 4 + wid;        // b*T + t
  const int b    = row >> 11, t = row & (T_ - 1);
  const float cs = fc[t * 64 + lane], sn = fs[t * 64 + lane];
  const float* base = qkv + (size_t)row * QKV_;

  #pragma unroll 2
  for (int h = 0; h < NH_; h++) {
    float2 ab = *(const float2*)(base + h * HD_ + 2 * lane);
    float oa = ab.x * cs - ab.y * sn;
    float ob = ab.x * sn + ab.y * cs;
    float ss = oa * oa + ob * ob;
    #pragma unroll
    for (int off = 32; off; off >>= 1) ss += __shfl_xor(ss, off);
    float rinv = rsqrtf(ss * (1.0f / HD_) + 1e-6f);
    bf16x2 o = { (__bf16)(oa * rinv * qw[2 * lane]), (__bf16)(ob * rinv * qw[2 * lane + 1]) };
    *(bf16x2*)&qn[(size_t)((b * NH_ + h) * T_ + t) * HD_ + 2 * lane] = o;
  }
  #pragma unroll 2
  for (int h = 0; h < KVH_; h++) {
    float2 ab = *(const float2*)(base + C_ + h * HD_ + 2 * lane);
    float oa = ab.x * cs - ab.y * sn;
    float ob = ab.x * sn + ab.y * cs;
    float ss = oa * oa + ob * ob;
    #pragma unroll
    for (int off = 32; off; off >>= 1) ss += __shfl_xor(ss, off);
    float rinv = rsqrtf(ss * (1.0f / HD_) + 1e-6f);
    bf16x2 o = { (__bf16)(oa * rinv * kw[2 * lane]), (__bf16)(ob * rinv * kw[2 * lane + 1]) };
    *(bf16x2*)&kn[(size_t)((b * KVH_ + h) * T_ + t) * HD_ + 2 * lane] = o;
  }
}

// ---------------- V transpose: qkv fp32 [t][d] -> vT bf16 [d][t], 64x64 LDS tiles ----
__global__ __launch_bounds__(256) void vtrans(const float* __restrict__ qkv,
                                              __bf16* __restrict__ vT) {
  __shared__ __bf16 L[64 * 68];
  const int tid = threadIdx.x;
  const int t0 = blockIdx.x * 64;
  const int d0 = blockIdx.y * 64;
  const int z  = blockIdx.z;            // b*KVH + hk
  const int b  = z >> 2, hk = z & 3;
  const int srcc = C_ + KVH_ * HD_ + hk * HD_ + d0;
  const int rr = tid >> 4, c4 = (tid & 15) * 4;
  #pragma unroll
  for (int i = 0; i < 4; i++) {
    int t = rr + i * 16;
    float4 f = *(const float4*)&qkv[(size_t)(b * T_ + t0 + t) * QKV_ + srcc + c4];
    bf16x4 o = { (__bf16)f.x, (__bf16)f.y, (__bf16)f.z, (__bf16)f.w };
    *(bf16x4*)&L[t * 68 + c4] = o;
  }
  __syncthreads();
  const int dr = tid >> 3, tc8 = (tid & 7) * 8;
  #pragma unroll
  for (int i = 0; i < 2; i++) {
    int d = dr + i * 32;
    bf16x8 ov;
    #pragma unroll
    for (int j = 0; j < 8; j++) ov[j] = L[(tc8 + j) * 68 + d];
    *(bf16x8*)&vT[(size_t)(z * HD_ + d0 + d) * T_ + t0 + tc8] = ov;
  }
}

// ---------------- causal flash attention, S^T layout, no P LDS round-trip ----------
// 1024 blocks (one 64-row Q-tile each, heavy-first). S^T = mfma(K,Q) puts q on
// lanes (col=r16): softmax reductions = in-lane tree + 2 shuffles; P repacked to
// PV A-fragment via 16 conflict-free ds_bpermutes. LDS = K/V only (32 KB).
__device__ __forceinline__ void kv_prefetch(const __bf16* kbase, const __bf16* vbase,
                                            int kt0, int wid, int lane,
                                            bf16x8 kreg[4], bf16x8 vreg[4]) {
  const int r4 = lane >> 2, c8 = (lane & 3) * 8;
  const __bf16* kg = kbase + (size_t)(kt0 + wid * 16 + r4) * HD_ + c8;
  #pragma unroll
  for (int cb = 0; cb < 4; cb++) kreg[cb] = *(const bf16x8*)(kg + cb * 32);
  #pragma unroll
  for (int s = 0; s < 2; s++) {
    const __bf16* vg = vbase + (size_t)((wid * 2 + s) * 16 + r4) * T_ + kt0 + c8;
    #pragma unroll
    for (int cb = 0; cb < 2; cb++) vreg[s * 2 + cb] = *(const bf16x8*)(vg + cb * 32);
  }
}

__device__ __forceinline__ void kv_commit(__bf16* Ks, __bf16* Vs, int wid, int lane,
                                          const bf16x8 kreg[4], const bf16x8 vreg[4]) {
  #pragma unroll
  for (int cb = 0; cb < 4; cb++)
    *(bf16x8*)(Ks + wid * 2048 + cb * 512 + lane * 8) = kreg[cb];
  #pragma unroll
  for (int s = 0; s < 2; s++)
    #pragma unroll
    for (int cb = 0; cb < 2; cb++)
      *(bf16x8*)(Vs + (wid * 2 + s) * 1024 + cb * 512 + lane * 8) = vreg[s * 2 + cb];
}

__global__ __launch_bounds__(256) void flash(const __bf16* __restrict__ q,
                                             const __bf16* __restrict__ k,
                                             const __bf16* __restrict__ vT,
                                             __bf16* __restrict__ y) {
  __shared__ __align__(16) __bf16 Ks[64 * 128];   // tiles (kt4,d4) of [16kt][32d]
  __shared__ __align__(16) __bf16 Vs[128 * 64];   // tiles (d8,kt2) of [16d][32kt]
  const int tid = threadIdx.x;
  const int wid = tid >> 6, lane = tid & 63, quad = lane >> 4, r16 = lane & 15;
  const int h = blockIdx.y, b = blockIdx.z;
  const int hk = h >> 2;
  const __bf16* kbase = k  + (size_t)(b * KVH_ + hk) * T_ * HD_;
  const __bf16* vbase = vT + (size_t)(b * KVH_ + hk) * HD_ * T_;
  const float sc = 0.08838834764831845f;  // 1/sqrt(128)
  const float NEG = -__builtin_inff();

  const int qt = 31 - blockIdx.x;   // heavy blocks dispatched first (LPT balance)
  const int nt = qt + 1;
  const int r0 = qt * 64 + wid * 16;
  const int rowq = r0 + r16;        // this lane's q-row (S^T layout: q = col = r16)

  const __bf16* qrow = q + ((size_t)(b * NH_ + h) * T_ + r0 + r16) * HD_;
  bf16x8 qf[4];
  #pragma unroll
  for (int kb = 0; kb < 4; kb++) qf[kb] = *(const bf16x8*)&qrow[kb * 32 + quad * 8];

  floatx4 o[8];
  #pragma unroll
  for (int j = 0; j < 8; j++) o[j] = (floatx4){0.f, 0.f, 0.f, 0.f};
  float m_r = NEG, l_r = 0.f;

  bf16x8 kreg[4], vreg[4];
  kv_prefetch(kbase, vbase, 0, wid, lane, kreg, vreg);

  #pragma unroll 1
  for (int it = 0; it < nt; ++it) {
    __syncthreads();
    kv_commit(Ks, Vs, wid, lane, kreg, vreg);
    __syncthreads();
    if (it + 1 < nt) kv_prefetch(kbase, vbase, (it + 1) * 64, wid, lane, kreg, vreg);

    const int kt0 = it * 64;
    // S^T[kt][q] = mfma(Kfrag as A, Qfrag as B): lane holds S[rowq][kt0+cb*16+quad*4+reg]
    floatx4 s[4];
    #pragma unroll
    for (int cb = 0; cb < 4; cb++) s[cb] = (floatx4){0.f, 0.f, 0.f, 0.f};
    #pragma unroll
    for (int kb = 0; kb < 4; kb++)
      #pragma unroll
      for (int cb = 0; cb < 4; cb++) {
        bf16x8 kf = *(const bf16x8*)&Ks[(cb * 4 + kb) * 512 + r16 * 32 + quad * 8];
        s[cb] = __builtin_amdgcn_mfma_f32_16x16x32_bf16(kf, qf[kb], s[cb], 0, 0, 0);
      }

    const bool last = (it == nt - 1);
    float mx = NEG;
    #pragma unroll
    for (int cb = 0; cb < 4; cb++)
      #pragma unroll
      for (int reg = 0; reg < 4; reg++) {
        float vv = s[cb][reg] * sc;
        if (last && (kt0 + cb * 16 + quad * 4 + reg > rowq)) vv = NEG;
        s[cb][reg] = vv;
        mx = fmaxf(mx, vv);
      }
    mx = fmaxf(mx, __shfl_xor(mx, 16));
    mx = fmaxf(mx, __shfl_xor(mx, 32));
    const float mnew = fmaxf(m_r, mx);
    const float alpha = __expf(m_r - mnew);
    m_r = mnew;

    float rs = 0.f;
    #pragma unroll
    for (int cb = 0; cb < 4; cb++)
      #pragma unroll
      for (int reg = 0; reg < 4; reg++) {
        float p = __expf(s[cb][reg] - mnew);
        s[cb][reg] = p;
        rs += p;
      }
    rs += __shfl_xor(rs, 16);
    rs += __shfl_xor(rs, 32);
    l_r = l_r * alpha + rs;

    int pk[4][2];
    #pragma unroll
    for (int cb = 0; cb < 4; cb++) {
      pk[cb][0] = pack2(s[cb][0], s[cb][1]);
      pk[cb][1] = pack2(s[cb][2], s[cb][3]);
    }

    float al[4];
    #pragma unroll
    for (int reg = 0; reg < 4; reg++) al[reg] = __shfl(alpha, quad * 4 + reg);
    #pragma unroll
    for (int reg = 0; reg < 4; reg++)
      #pragma unroll
      for (int j = 0; j < 8; j++) o[j][reg] *= al[reg];

    // Repack P (held as S^T fragments) into PV A-fragment via cross-quad bpermute.
    // Target lane (Q=quad, r16) needs A[m=r16][k=Q*8+j] (+half*32).
    const int srcA = ((quad & 1) << 5) + r16;   // src quad 2*(Q&1)
    const int srcB = srcA + 16;                 // src quad 2*(Q&1)+1
    const bool hi = quad >= 2;                  // cb select: half*2 + (Q>>1)
    #pragma unroll
    for (int half = 0; half < 2; half++) {
      const int c0 = half * 2, c1 = half * 2 + 1;
      int a0 = __shfl(pk[c0][0], srcA), b0 = __shfl(pk[c1][0], srcA);
      int a1 = __shfl(pk[c0][1], srcA), b1 = __shfl(pk[c1][1], srcA);
      int a2 = __shfl(pk[c0][0], srcB), b2 = __shfl(pk[c1][0], srcB);
      int a3 = __shfl(pk[c0][1], srcB), b3 = __shfl(pk[c1][1], srcB);
      union { int i[4]; bf16x8 v; } u;
      u.i[0] = hi ? b0 : a0;
      u.i[1] = hi ? b1 : a1;
      u.i[2] = hi ? b2 : a2;
      u.i[3] = hi ? b3 : a3;
      #pragma unroll
      for (int j = 0; j < 8; j++) {
        bf16x8 vf = *(const bf16x8*)&Vs[(j * 2 + half) * 512 + r16 * 32 + quad * 8];
        o[j] = __builtin_amdgcn_mfma_f32_16x16x32_bf16(u.v, vf, o[j], 0, 0, 0);
      }
    }
  }

  #pragma unroll
  for (int reg = 0; reg < 4; reg++) {
    int trow = r0 + quad * 4 + reg;
    float lf = __shfl(l_r, quad * 4 + reg);
    float inv = 1.0f / lf;
    __bf16* yr = y + ((size_t)(b * T_) + trow) * C_ + h * HD_;
    #pragma unroll
    for (int j = 0; j < 8; j++) yr[j * 16 + r16] = (__bf16)(o[j][reg] * inv);
  }
}

extern "C" void kernel_launch(void* const* d_in, const int* in_sizes, int n_in,
                              void* d_out, int out_size, void* d_ws, size_t ws_size,
                              hipStream_t stream) {
  const float* x     = (const float*)d_in[0];
  const float* wqkv  = (const float*)d_in[1];
  const float* wproj = (const float*)d_in[2];
  const float* qw    = (const float*)d_in[3];
  const float* kw    = (const float*)d_in[4];
  const float* fc    = (const float*)d_in[5];
  const float* fs    = (const float*)d_in[6];
  float* out = (float*)d_out;

  char* w = (char*)d_ws;
  __bf16* xb     = (__bf16*)w; w += (size_t)M_ * C_ * 2;
  __bf16* wqkvb  = (__bf16*)w; w += (size_t)QKV_ * C_ * 2;
  __bf16* wprojb = (__bf16*)w; w += (size_t)C_ * C_ * 2;
  float*  qkv    = (float*)w;  w += (size_t)M_ * QKV_ * 4;
  __bf16* qn     = (__bf16*)w; w += (size_t)B_ * NH_ * T_ * HD_ * 2;
  __bf16* kn     = (__bf16*)w; w += (size_t)B_ * KVH_ * T_ * HD_ * 2;
  __bf16* vT     = (__bf16*)w; w += (size_t)B_ * KVH_ * T_ * HD_ * 2;
  __bf16* ybf    = (__bf16*)w; w += (size_t)M_ * C_ * 2;

  cvt_bf16<<<M_ * C_ / 4 / 256, 256, 0, stream>>>(x, xb, M_ * C_ / 4);
  cvt_bf16<<<QKV_ * C_ / 4 / 256, 256, 0, stream>>>(wqkv, wqkvb, QKV_ * C_ / 4);
  cvt_bf16<<<C_ * C_ / 4 / 256, 256, 0, stream>>>(wproj, wprojb, C_ * C_ / 4);

  gemm_bt<<<dim3(QKV_ / 128, M_ / 128), 256, 0, stream>>>(xb, wqkvb, qkv, QKV_, C_);
  rope_norm<<<M_ / 4, 256, 0, stream>>>(qkv, qw, kw, fc, fs, qn, kn);
  vtrans<<<dim3(T_ / 64, HD_ / 64, B_ * KVH_), 256, 0, stream>>>(qkv, vT);
  flash<<<dim3(32, NH_, B_), 256, 0, stream>>>(qn, kn, vT, ybf);
  gemm_bt<<<dim3(C_ / 128, M_ / 128), 256, 0, stream>>>(ybf, wprojb, out, C_, C_);
}

// Round 5
// 367.239 us; speedup vs baseline: 1.1531x; 1.1531x over previous
//
#include <hip/hip_runtime.h>
#include <hip/hip_bf16.h>

#define B_    2
#define T_    2048
#define C_    2048
#define NH_   16
#define KVH_  4
#define HD_   128
#define QKV_  3072
#define M_    4096

typedef float  floatx4 __attribute__((ext_vector_type(4)));
typedef __bf16 bf16x8  __attribute__((ext_vector_type(8)));
typedef __bf16 bf16x4  __attribute__((ext_vector_type(4)));
typedef __bf16 bf16x2  __attribute__((ext_vector_type(2)));

typedef const __attribute__((address_space(1))) void* gas_t;
typedef __attribute__((address_space(3))) void*       las_t;
__device__ __forceinline__ void gl_lds16(const void* g, void* l) {
  __builtin_amdgcn_global_load_lds((gas_t)g, (las_t)l, 16, 0, 0);
}

// ---------------- fp32 -> bf16 conversion (memory-bound) ----------------
__global__ __launch_bounds__(256) void cvt_bf16(const float* __restrict__ src,
                                                __bf16* __restrict__ dst, int n4) {
  int i = blockIdx.x * blockDim.x + threadIdx.x;
  if (i < n4) {
    float4 f = ((const float4*)src)[i];
    bf16x4 o = { (__bf16)f.x, (__bf16)f.y, (__bf16)f.z, (__bf16)f.w };
    ((bf16x4*)dst)[i] = o;
  }
}

// ---------------- C = A[M][K] * B[N][K]^T, fp32 out ----------------
// m97 structure, BK=64 staged as two BK=32 sub-buffers (same bank layout),
// halving the barrier count: 32 MFMAs per sync window.
__global__ __launch_bounds__(256) void gemm_bt(const __bf16* __restrict__ A,
                                               const __bf16* __restrict__ Bm,
                                               float* __restrict__ Cc,
                                               int N, int K) {
  __shared__ __align__(16) __bf16 As[2][128 * 32];
  __shared__ __align__(16) __bf16 Bs[2][128 * 32];
  const int tid  = threadIdx.x;
  const int wid  = tid >> 6, lane = tid & 63, quad = lane >> 4, r16 = lane & 15;
  const int bm   = blockIdx.y * 128, bn = blockIdx.x * 128;
  const int wm   = (wid >> 1) * 64, wn = (wid & 1) * 64;
  const int srow = wid * 16 + (lane >> 2);
  const int scol = (lane & 3) * 8;
  const __bf16* aptr = A  + (size_t)(bm + srow) * K + scol;
  const __bf16* bptr = Bm + (size_t)(bn + srow) * K + scol;
  const size_t rowskip = (size_t)64 * K;

  floatx4 acc[4][4];
  #pragma unroll
  for (int i = 0; i < 4; i++)
    #pragma unroll
    for (int j = 0; j < 4; j++) acc[i][j] = (floatx4){0.f, 0.f, 0.f, 0.f};

  for (int k0 = 0; k0 < K; k0 += 64) {
    #pragma unroll
    for (int hf = 0; hf < 2; hf++) {
      gl_lds16(aptr + k0 + hf * 32,           &As[hf][wid * 512]);
      gl_lds16(aptr + rowskip + k0 + hf * 32, &As[hf][2048 + wid * 512]);
      gl_lds16(bptr + k0 + hf * 32,           &Bs[hf][wid * 512]);
      gl_lds16(bptr + rowskip + k0 + hf * 32, &Bs[hf][2048 + wid * 512]);
    }
    __syncthreads();

    #pragma unroll
    for (int hf = 0; hf < 2; hf++) {
      bf16x8 af[4], bfr[4];
      #pragma unroll
      for (int i = 0; i < 4; i++) af[i]  = *(const bf16x8*)&As[hf][(wm + i * 16 + r16) * 32 + quad * 8];
      #pragma unroll
      for (int j = 0; j < 4; j++) bfr[j] = *(const bf16x8*)&Bs[hf][(wn + j * 16 + r16) * 32 + quad * 8];
      #pragma unroll
      for (int i = 0; i < 4; i++)
        #pragma unroll
        for (int j = 0; j < 4; j++)
          acc[i][j] = __builtin_amdgcn_mfma_f32_16x16x32_bf16(af[i], bfr[j], acc[i][j], 0, 0, 0);
    }
    __syncthreads();
  }

  #pragma unroll
  for (int i = 0; i < 4; i++) {
    #pragma unroll
    for (int reg = 0; reg < 4; reg++) {
      int row = bm + wm + i * 16 + quad * 4 + reg;
      float* crow = Cc + (size_t)row * N + bn + wn;
      #pragma unroll
      for (int j = 0; j < 4; j++) crow[j * 16 + r16] = acc[i][j][reg];
    }
  }
}

// ---------------- RoPE + RMSNorm, one wave per (b,t) row ----------------
__global__ __launch_bounds__(256) void rope_norm(const float* __restrict__ qkv,
                                                 const float* __restrict__ qw,
                                                 const float* __restrict__ kw,
                                                 const float* __restrict__ fc,
                                                 const float* __restrict__ fs,
                                                 __bf16* __restrict__ qn,
                                                 __bf16* __restrict__ kn) {
  const int tid  = threadIdx.x;
  const int wid  = tid >> 6, lane = tid & 63;
  const int row  = blockIdx.x * 4 + wid;        // b*T + t
  const int b    = row >> 11, t = row & (T_ - 1);
  const float cs = fc[t * 64 + lane], sn = fs[t * 64 + lane];
  const float* base = qkv + (size_t)row * QKV_;

  #pragma unroll 2
  for (int h = 0; h < NH_; h++) {
    float2 ab = *(const float2*)(base + h * HD_ + 2 * lane);
    float oa = ab.x * cs - ab.y * sn;
    float ob = ab.x * sn + ab.y * cs;
    float ss = oa * oa + ob * ob;
    #pragma unroll
    for (int off = 32; off; off >>= 1) ss += __shfl_xor(ss, off);
    float rinv = rsqrtf(ss * (1.0f / HD_) + 1e-6f);
    bf16x2 o = { (__bf16)(oa * rinv * qw[2 * lane]), (__bf16)(ob * rinv * qw[2 * lane + 1]) };
    *(bf16x2*)&qn[(size_t)((b * NH_ + h) * T_ + t) * HD_ + 2 * lane] = o;
  }
  #pragma unroll 2
  for (int h = 0; h < KVH_; h++) {
    float2 ab = *(const float2*)(base + C_ + h * HD_ + 2 * lane);
    float oa = ab.x * cs - ab.y * sn;
    float ob = ab.x * sn + ab.y * cs;
    float ss = oa * oa + ob * ob;
    #pragma unroll
    for (int off = 32; off; off >>= 1) ss += __shfl_xor(ss, off);
    float rinv = rsqrtf(ss * (1.0f / HD_) + 1e-6f);
    bf16x2 o = { (__bf16)(oa * rinv * kw[2 * lane]), (__bf16)(ob * rinv * kw[2 * lane + 1]) };
    *(bf16x2*)&kn[(size_t)((b * KVH_ + h) * T_ + t) * HD_ + 2 * lane] = o;
  }
}

// ---------------- V transpose: qkv fp32 [t][d] -> vT bf16 [d][t], 64x64 LDS tiles ----
__global__ __launch_bounds__(256) void vtrans(const float* __restrict__ qkv,
                                              __bf16* __restrict__ vT) {
  __shared__ __bf16 L[64 * 68];
  const int tid = threadIdx.x;
  const int t0 = blockIdx.x * 64;
  const int d0 = blockIdx.y * 64;
  const int z  = blockIdx.z;            // b*KVH + hk
  const int b  = z >> 2, hk = z & 3;
  const int srcc = C_ + KVH_ * HD_ + hk * HD_ + d0;
  const int rr = tid >> 4, c4 = (tid & 15) * 4;
  #pragma unroll
  for (int i = 0; i < 4; i++) {
    int t = rr + i * 16;
    float4 f = *(const float4*)&qkv[(size_t)(b * T_ + t0 + t) * QKV_ + srcc + c4];
    bf16x4 o = { (__bf16)f.x, (__bf16)f.y, (__bf16)f.z, (__bf16)f.w };
    *(bf16x4*)&L[t * 68 + c4] = o;
  }
  __syncthreads();
  const int dr = tid >> 3, tc8 = (tid & 7) * 8;
  #pragma unroll
  for (int i = 0; i < 2; i++) {
    int d = dr + i * 32;
    bf16x8 ov;
    #pragma unroll
    for (int j = 0; j < 8; j++) ov[j] = L[(tc8 + j) * 68 + d];
    *(bf16x8*)&vT[(size_t)(z * HD_ + d0 + d) * T_ + t0 + tc8] = ov;
  }
}

// ---------------- causal flash attention: 128 Q-rows/block ----------------
// 4 waves x 32 rows (two 16-row subtiles). K-tile 64 in shared LDS; each kf/vf
// LDS read feeds both subtiles (halves LDS traffic/row vs 64-row blocks).
// Heavy-first 1-D grid (LPT). R3-proven P round-trip + ones-MFMA rowsum.
__device__ __forceinline__ void kv_prefetch(const __bf16* kbase, const __bf16* vbase,
                                            int kt0, int wid, int lane,
                                            bf16x8 kreg[4], bf16x8 vreg[4]) {
  const int r4 = lane >> 2, c8 = (lane & 3) * 8;
  const __bf16* kg = kbase + (size_t)(kt0 + wid * 16 + r4) * HD_ + c8;
  #pragma unroll
  for (int cb = 0; cb < 4; cb++) kreg[cb] = *(const bf16x8*)(kg + cb * 32);
  #pragma unroll
  for (int s = 0; s < 2; s++) {
    const __bf16* vg = vbase + (size_t)((wid * 2 + s) * 16 + r4) * T_ + kt0 + c8;
    #pragma unroll
    for (int cb = 0; cb < 2; cb++) vreg[s * 2 + cb] = *(const bf16x8*)(vg + cb * 32);
  }
}

__device__ __forceinline__ void kv_commit(__bf16* Ks, __bf16* Vs, int wid, int lane,
                                          const bf16x8 kreg[4], const bf16x8 vreg[4]) {
  #pragma unroll
  for (int cb = 0; cb < 4; cb++)
    *(bf16x8*)(Ks + wid * 2048 + cb * 512 + lane * 8) = kreg[cb];
  #pragma unroll
  for (int s = 0; s < 2; s++)
    #pragma unroll
    for (int cb = 0; cb < 2; cb++)
      *(bf16x8*)(Vs + (wid * 2 + s) * 1024 + cb * 512 + lane * 8) = vreg[s * 2 + cb];
}

__global__ __launch_bounds__(256, 2) void flash(const __bf16* __restrict__ q,
                                                const __bf16* __restrict__ k,
                                                const __bf16* __restrict__ vT,
                                                __bf16* __restrict__ y) {
  __shared__ __align__(16) __bf16 Ks[64 * 128];      // tiles of [16kt][32d]
  __shared__ __align__(16) __bf16 Vs[128 * 64];      // tiles of [16d][32kt]
  __shared__ __align__(16) __bf16 Ps[4][2][16 * 72]; // per-wave, per-subtile P
  const int tid = threadIdx.x;
  const int wid = tid >> 6, lane = tid & 63, quad = lane >> 4, r16 = lane & 15;
  const int x   = blockIdx.x;
  const int qt  = 15 - (x >> 5);        // heavy blocks dispatched first (LPT)
  const int hl  = x & 31;
  const int b   = hl >> 4, h = hl & 15, hk = h >> 2;
  const int nt  = 2 * (qt + 1);
  const int r0w = qt * 128 + wid * 32;  // this wave's first q-row

  const __bf16* kbase = k  + (size_t)(b * KVH_ + hk) * T_ * HD_;
  const __bf16* vbase = vT + (size_t)(b * KVH_ + hk) * HD_ * T_;
  const float sc = 0.08838834764831845f;  // 1/sqrt(128)
  const float NEG = -__builtin_inff();
  bf16x8 ones;
  #pragma unroll
  for (int i = 0; i < 8; i++) ones[i] = (__bf16)1.0f;

  bf16x8 qf[2][4];
  #pragma unroll
  for (int s = 0; s < 2; s++) {
    const __bf16* qrow = q + ((size_t)(b * NH_ + h) * T_ + r0w + s * 16 + r16) * HD_;
    #pragma unroll
    for (int kb = 0; kb < 4; kb++) qf[s][kb] = *(const bf16x8*)&qrow[kb * 32 + quad * 8];
  }

  floatx4 o[2][8], ol[2];
  #pragma unroll
  for (int s = 0; s < 2; s++) {
    ol[s] = (floatx4){0.f, 0.f, 0.f, 0.f};
    #pragma unroll
    for (int j = 0; j < 8; j++) o[s][j] = (floatx4){0.f, 0.f, 0.f, 0.f};
  }
  float m_r[2][4] = {{NEG, NEG, NEG, NEG}, {NEG, NEG, NEG, NEG}};

  bf16x8 kreg[4], vreg[4];
  kv_prefetch(kbase, vbase, 0, wid, lane, kreg, vreg);

  #pragma unroll 1
  for (int it = 0; it < nt; ++it) {
    __syncthreads();
    kv_commit(Ks, Vs, wid, lane, kreg, vreg);
    __syncthreads();
    if (it + 1 < nt) kv_prefetch(kbase, vbase, (it + 1) * 64, wid, lane, kreg, vreg);

    const int kt0 = it * 64;
    if (kt0 > r0w + 31) continue;     // wave-uniform: tile fully masked for this wave

    floatx4 sv[2][4];
    #pragma unroll
    for (int s = 0; s < 2; s++)
      #pragma unroll
      for (int cb = 0; cb < 4; cb++) sv[s][cb] = (floatx4){0.f, 0.f, 0.f, 0.f};
    #pragma unroll
    for (int kb = 0; kb < 4; kb++)
      #pragma unroll
      for (int cb = 0; cb < 4; cb++) {
        bf16x8 kf = *(const bf16x8*)&Ks[(cb * 4 + kb) * 512 + r16 * 32 + quad * 8];
        sv[0][cb] = __builtin_amdgcn_mfma_f32_16x16x32_bf16(qf[0][kb], kf, sv[0][cb], 0, 0, 0);
        sv[1][cb] = __builtin_amdgcn_mfma_f32_16x16x32_bf16(qf[1][kb], kf, sv[1][cb], 0, 0, 0);
      }

    const bool needmask = (kt0 + 64 > r0w);  // wave-uniform
    float alpha[2][4];
    #pragma unroll
    for (int s = 0; s < 2; s++) {
      __bf16* Pw = Ps[wid][s];
      #pragma unroll
      for (int reg = 0; reg < 4; reg++) {
        const int rowq = r0w + s * 16 + quad * 4 + reg;
        float v0 = sv[s][0][reg] * sc, v1 = sv[s][1][reg] * sc;
        float v2 = sv[s][2][reg] * sc, v3 = sv[s][3][reg] * sc;
        if (needmask) {
          if (kt0 +      r16 > rowq) v0 = NEG;
          if (kt0 + 16 + r16 > rowq) v1 = NEG;
          if (kt0 + 32 + r16 > rowq) v2 = NEG;
          if (kt0 + 48 + r16 > rowq) v3 = NEG;
        }
        float mx = fmaxf(fmaxf(v0, v1), fmaxf(v2, v3));
        #pragma unroll
        for (int off = 8; off; off >>= 1) mx = fmaxf(mx, __shfl_xor(mx, off));
        float mnew = fmaxf(m_r[s][reg], mx);
        alpha[s][reg] = __expf(m_r[s][reg] - mnew);
        m_r[s][reg] = mnew;
        Pw[(quad * 4 + reg) * 72 +      r16] = (__bf16)__expf(v0 - mnew);
        Pw[(quad * 4 + reg) * 72 + 16 + r16] = (__bf16)__expf(v1 - mnew);
        Pw[(quad * 4 + reg) * 72 + 32 + r16] = (__bf16)__expf(v2 - mnew);
        Pw[(quad * 4 + reg) * 72 + 48 + r16] = (__bf16)__expf(v3 - mnew);
      }
    }
    #pragma unroll
    for (int s = 0; s < 2; s++)
      #pragma unroll
      for (int reg = 0; reg < 4; reg++) {
        ol[s][reg] *= alpha[s][reg];
        #pragma unroll
        for (int j = 0; j < 8; j++) o[s][j][reg] *= alpha[s][reg];
      }
    __asm__ volatile("" ::: "memory");          // wave-private P: writes before reads
    bf16x8 pf[2][2];
    #pragma unroll
    for (int s = 0; s < 2; s++) {
      pf[s][0] = *(const bf16x8*)&Ps[wid][s][r16 * 72 + quad * 8];
      pf[s][1] = *(const bf16x8*)&Ps[wid][s][r16 * 72 + 32 + quad * 8];
      ol[s] = __builtin_amdgcn_mfma_f32_16x16x32_bf16(pf[s][0], ones, ol[s], 0, 0, 0);
      ol[s] = __builtin_amdgcn_mfma_f32_16x16x32_bf16(pf[s][1], ones, ol[s], 0, 0, 0);
    }
    #pragma unroll
    for (int j = 0; j < 8; j++) {
      bf16x8 vf0 = *(const bf16x8*)&Vs[(j * 2 + 0) * 512 + r16 * 32 + quad * 8];
      bf16x8 vf1 = *(const bf16x8*)&Vs[(j * 2 + 1) * 512 + r16 * 32 + quad * 8];
      o[0][j] = __builtin_amdgcn_mfma_f32_16x16x32_bf16(pf[0][0], vf0, o[0][j], 0, 0, 0);
      o[0][j] = __builtin_amdgcn_mfma_f32_16x16x32_bf16(pf[0][1], vf1, o[0][j], 0, 0, 0);
      o[1][j] = __builtin_amdgcn_mfma_f32_16x16x32_bf16(pf[1][0], vf0, o[1][j], 0, 0, 0);
      o[1][j] = __builtin_amdgcn_mfma_f32_16x16x32_bf16(pf[1][1], vf1, o[1][j], 0, 0, 0);
    }
  }

  #pragma unroll
  for (int s = 0; s < 2; s++)
    #pragma unroll
    for (int reg = 0; reg < 4; reg++) {
      int trow = r0w + s * 16 + quad * 4 + reg;
      float inv = 1.0f / ol[s][reg];
      __bf16* yr = y + ((size_t)(b * T_) + trow) * C_ + h * HD_;
      #pragma unroll
      for (int j = 0; j < 8; j++) yr[j * 16 + r16] = (__bf16)(o[s][j][reg] * inv);
    }
}

extern "C" void kernel_launch(void* const* d_in, const int* in_sizes, int n_in,
                              void* d_out, int out_size, void* d_ws, size_t ws_size,
                              hipStream_t stream) {
  const float* x     = (const float*)d_in[0];
  const float* wqkv  = (const float*)d_in[1];
  const float* wproj = (const float*)d_in[2];
  const float* qw    = (const float*)d_in[3];
  const float* kw    = (const float*)d_in[4];
  const float* fc    = (const float*)d_in[5];
  const float* fs    = (const float*)d_in[6];
  float* out = (float*)d_out;

  char* w = (char*)d_ws;
  __bf16* xb     = (__bf16*)w; w += (size_t)M_ * C_ * 2;
  __bf16* wqkvb  = (__bf16*)w; w += (size_t)QKV_ * C_ * 2;
  __bf16* wprojb = (__bf16*)w; w += (size_t)C_ * C_ * 2;
  float*  qkv    = (float*)w;  w += (size_t)M_ * QKV_ * 4;
  __bf16* qn     = (__bf16*)w; w += (size_t)B_ * NH_ * T_ * HD_ * 2;
  __bf16* kn     = (__bf16*)w; w += (size_t)B_ * KVH_ * T_ * HD_ * 2;
  __bf16* vT     = (__bf16*)w; w += (size_t)B_ * KVH_ * T_ * HD_ * 2;
  __bf16* ybf    = (__bf16*)w; w += (size_t)M_ * C_ * 2;

  cvt_bf16<<<M_ * C_ / 4 / 256, 256, 0, stream>>>(x, xb, M_ * C_ / 4);
  cvt_bf16<<<QKV_ * C_ / 4 / 256, 256, 0, stream>>>(wqkv, wqkvb, QKV_ * C_ / 4);
  cvt_bf16<<<C_ * C_ / 4 / 256, 256, 0, stream>>>(wproj, wprojb, C_ * C_ / 4);

  gemm_bt<<<dim3(QKV_ / 128, M_ / 128), 256, 0, stream>>>(xb, wqkvb, qkv, QKV_, C_);
  rope_norm<<<M_ / 4, 256, 0, stream>>>(qkv, qw, kw, fc, fs, qn, kn);
  vtrans<<<dim3(T_ / 64, HD_ / 64, B_ * KVH_), 256, 0, stream>>>(qkv, vT);
  flash<<<dim3(512), 256, 0, stream>>>(qn, kn, vT, ybf);
  gemm_bt<<<dim3(C_ / 128, M_ / 128), 256, 0, stream>>>(ybf, wprojb, out, C_, C_);
}

// Round 6
// 327.360 us; speedup vs baseline: 1.2936x; 1.1218x over previous
//
#include <hip/hip_runtime.h>
#include <hip/hip_bf16.h>

#define B_    2
#define T_    2048
#define C_    2048
#define NH_   16
#define KVH_  4
#define HD_   128
#define QKV_  3072
#define M_    4096

typedef float  floatx4 __attribute__((ext_vector_type(4)));
typedef __bf16 bf16x8  __attribute__((ext_vector_type(8)));
typedef __bf16 bf16x4  __attribute__((ext_vector_type(4)));
typedef __bf16 bf16x2  __attribute__((ext_vector_type(2)));

typedef const __attribute__((address_space(1))) void* gas_t;
typedef __attribute__((address_space(3))) void*       las_t;
__device__ __forceinline__ void gl_lds16(const void* g, void* l) {
  __builtin_amdgcn_global_load_lds((gas_t)g, (las_t)l, 16, 0, 0);
}

// ---------------- fp32 -> bf16 conversion, all three tensors in one launch ----------
__global__ __launch_bounds__(256) void cvt3(const float* __restrict__ s0, __bf16* __restrict__ d0, int n0,
                                            const float* __restrict__ s1, __bf16* __restrict__ d1, int n1,
                                            const float* __restrict__ s2, __bf16* __restrict__ d2, int n2) {
  int i = blockIdx.x * blockDim.x + threadIdx.x;
  const float* s; __bf16* d;
  if (i < n0) { s = s0; d = d0; }
  else {
    i -= n0;
    if (i < n1) { s = s1; d = d1; }
    else { i -= n1; if (i >= n2) return; s = s2; d = d2; }
  }
  float4 f = ((const float4*)s)[i];
  bf16x4 o = { (__bf16)f.x, (__bf16)f.y, (__bf16)f.z, (__bf16)f.w };
  ((bf16x4*)d)[i] = o;
}

// ---------------- C = A[M][K] * B[N][K]^T, templated output dtype ----------------
// m97 structure, BK=64 staged as two BK=32 sub-buffers: 32 MFMAs per sync window.
template <typename OutT>
__global__ __launch_bounds__(256) void gemm_bt(const __bf16* __restrict__ A,
                                               const __bf16* __restrict__ Bm,
                                               OutT* __restrict__ Cc,
                                               int N, int K) {
  __shared__ __align__(16) __bf16 As[2][128 * 32];
  __shared__ __align__(16) __bf16 Bs[2][128 * 32];
  const int tid  = threadIdx.x;
  const int wid  = tid >> 6, lane = tid & 63, quad = lane >> 4, r16 = lane & 15;
  const int bm   = blockIdx.y * 128, bn = blockIdx.x * 128;
  const int wm   = (wid >> 1) * 64, wn = (wid & 1) * 64;
  const int srow = wid * 16 + (lane >> 2);
  const int scol = (lane & 3) * 8;
  const __bf16* aptr = A  + (size_t)(bm + srow) * K + scol;
  const __bf16* bptr = Bm + (size_t)(bn + srow) * K + scol;
  const size_t rowskip = (size_t)64 * K;

  floatx4 acc[4][4];
  #pragma unroll
  for (int i = 0; i < 4; i++)
    #pragma unroll
    for (int j = 0; j < 4; j++) acc[i][j] = (floatx4){0.f, 0.f, 0.f, 0.f};

  for (int k0 = 0; k0 < K; k0 += 64) {
    #pragma unroll
    for (int hf = 0; hf < 2; hf++) {
      gl_lds16(aptr + k0 + hf * 32,           &As[hf][wid * 512]);
      gl_lds16(aptr + rowskip + k0 + hf * 32, &As[hf][2048 + wid * 512]);
      gl_lds16(bptr + k0 + hf * 32,           &Bs[hf][wid * 512]);
      gl_lds16(bptr + rowskip + k0 + hf * 32, &Bs[hf][2048 + wid * 512]);
    }
    __syncthreads();

    #pragma unroll
    for (int hf = 0; hf < 2; hf++) {
      bf16x8 af[4], bfr[4];
      #pragma unroll
      for (int i = 0; i < 4; i++) af[i]  = *(const bf16x8*)&As[hf][(wm + i * 16 + r16) * 32 + quad * 8];
      #pragma unroll
      for (int j = 0; j < 4; j++) bfr[j] = *(const bf16x8*)&Bs[hf][(wn + j * 16 + r16) * 32 + quad * 8];
      #pragma unroll
      for (int i = 0; i < 4; i++)
        #pragma unroll
        for (int j = 0; j < 4; j++)
          acc[i][j] = __builtin_amdgcn_mfma_f32_16x16x32_bf16(af[i], bfr[j], acc[i][j], 0, 0, 0);
    }
    __syncthreads();
  }

  #pragma unroll
  for (int i = 0; i < 4; i++) {
    #pragma unroll
    for (int reg = 0; reg < 4; reg++) {
      int row = bm + wm + i * 16 + quad * 4 + reg;
      OutT* crow = Cc + (size_t)row * N + bn + wn;
      #pragma unroll
      for (int j = 0; j < 4; j++) crow[j * 16 + r16] = (OutT)acc[i][j][reg];
    }
  }
}

// ---------------- RoPE + RMSNorm (bf16 qkv input), one wave per (b,t) row ----------
__global__ __launch_bounds__(256) void rope_norm(const __bf16* __restrict__ qkv,
                                                 const float* __restrict__ qw,
                                                 const float* __restrict__ kw,
                                                 const float* __restrict__ fc,
                                                 const float* __restrict__ fs,
                                                 __bf16* __restrict__ qn,
                                                 __bf16* __restrict__ kn) {
  const int tid  = threadIdx.x;
  const int wid  = tid >> 6, lane = tid & 63;
  const int row  = blockIdx.x * 4 + wid;        // b*T + t
  const int b    = row >> 11, t = row & (T_ - 1);
  const float cs = fc[t * 64 + lane], sn = fs[t * 64 + lane];
  const __bf16* base = qkv + (size_t)row * QKV_;

  #pragma unroll 2
  for (int h = 0; h < NH_; h++) {
    bf16x2 ab = *(const bf16x2*)(base + h * HD_ + 2 * lane);
    float ax = (float)ab[0], ay = (float)ab[1];
    float oa = ax * cs - ay * sn;
    float ob = ax * sn + ay * cs;
    float ss = oa * oa + ob * ob;
    #pragma unroll
    for (int off = 32; off; off >>= 1) ss += __shfl_xor(ss, off);
    float rinv = rsqrtf(ss * (1.0f / HD_) + 1e-6f);
    bf16x2 o = { (__bf16)(oa * rinv * qw[2 * lane]), (__bf16)(ob * rinv * qw[2 * lane + 1]) };
    *(bf16x2*)&qn[(size_t)((b * NH_ + h) * T_ + t) * HD_ + 2 * lane] = o;
  }
  #pragma unroll 2
  for (int h = 0; h < KVH_; h++) {
    bf16x2 ab = *(const bf16x2*)(base + C_ + h * HD_ + 2 * lane);
    float ax = (float)ab[0], ay = (float)ab[1];
    float oa = ax * cs - ay * sn;
    float ob = ax * sn + ay * cs;
    float ss = oa * oa + ob * ob;
    #pragma unroll
    for (int off = 32; off; off >>= 1) ss += __shfl_xor(ss, off);
    float rinv = rsqrtf(ss * (1.0f / HD_) + 1e-6f);
    bf16x2 o = { (__bf16)(oa * rinv * kw[2 * lane]), (__bf16)(ob * rinv * kw[2 * lane + 1]) };
    *(bf16x2*)&kn[(size_t)((b * KVH_ + h) * T_ + t) * HD_ + 2 * lane] = o;
  }
}

// ---------------- V transpose: qkv bf16 [t][d] -> vT bf16 [d][t], 64x64 LDS tiles ----
__global__ __launch_bounds__(256) void vtrans(const __bf16* __restrict__ qkv,
                                              __bf16* __restrict__ vT) {
  __shared__ __bf16 L[64 * 68];
  const int tid = threadIdx.x;
  const int t0 = blockIdx.x * 64;
  const int d0 = blockIdx.y * 64;
  const int z  = blockIdx.z;            // b*KVH + hk
  const int b  = z >> 2, hk = z & 3;
  const int srcc = C_ + KVH_ * HD_ + hk * HD_ + d0;
  const int rr = tid >> 4, c4 = (tid & 15) * 4;
  #pragma unroll
  for (int i = 0; i < 4; i++) {
    int t = rr + i * 16;
    bf16x4 f = *(const bf16x4*)&qkv[(size_t)(b * T_ + t0 + t) * QKV_ + srcc + c4];
    *(bf16x4*)&L[t * 68 + c4] = f;
  }
  __syncthreads();
  const int dr = tid >> 3, tc8 = (tid & 7) * 8;
  #pragma unroll
  for (int i = 0; i < 2; i++) {
    int d = dr + i * 32;
    bf16x8 ov;
    #pragma unroll
    for (int j = 0; j < 8; j++) ov[j] = L[(tc8 + j) * 68 + d];
    *(bf16x8*)&vT[(size_t)(z * HD_ + d0 + d) * T_ + t0 + tc8] = ov;
  }
}

// ---------------- causal flash attention: 512 threads, 8 waves x 16 rows ----------
// Block = one (b,h) with a PAIR of 128-row Q-tiles (qt = 15-p then p) processed
// sequentially -> every block does exactly 34 K-tiles (perfect balance), grid = 256
// (1 block/CU, 8 waves). All 8 waves share one Ks/Vs staging; VGPR prefetch of
// tile it+1 during compute of tile it. Wave-level causal skip sits between the
// barriers; commit is unconditional so other waves' tiles are always staged.
__device__ __forceinline__ void kv_prefetch8(const __bf16* kbase, const __bf16* vbase,
                                             int kt0, int wid, int lane,
                                             bf16x8 kreg[2], bf16x8 vreg[2]) {
  const int r4 = lane >> 2, c8 = (lane & 3) * 8;
  #pragma unroll
  for (int i = 0; i < 2; i++) {
    const int n = wid * 2 + i;   // K tile: kt4 = n>>2 (16 kt rows), d4 = n&3 (32 d cols)
    kreg[i] = *(const bf16x8*)&kbase[(size_t)(kt0 + (n >> 2) * 16 + r4) * HD_ + (n & 3) * 32 + c8];
    vreg[i] = *(const bf16x8*)&vbase[(size_t)((n >> 1) * 16 + r4) * T_ + kt0 + (n & 1) * 32 + c8];
  }
}

__device__ __forceinline__ void kv_commit8(__bf16* Ks, __bf16* Vs, int wid, int lane,
                                           const bf16x8 kreg[2], const bf16x8 vreg[2]) {
  #pragma unroll
  for (int i = 0; i < 2; i++) {
    *(bf16x8*)(Ks + (wid * 2 + i) * 512 + lane * 8) = kreg[i];
    *(bf16x8*)(Vs + (wid * 2 + i) * 512 + lane * 8) = vreg[i];
  }
}

__global__ __launch_bounds__(512, 2) void flash(const __bf16* __restrict__ q,
                                                const __bf16* __restrict__ k,
                                                const __bf16* __restrict__ vT,
                                                __bf16* __restrict__ y) {
  __shared__ __align__(16) __bf16 Ks[64 * 128];   // 16 tiles of [16kt][32d]
  __shared__ __align__(16) __bf16 Vs[128 * 64];   // 16 tiles of [16d][32kt]
  __shared__ __align__(16) __bf16 Ps[8][16 * 72]; // per-wave P scratch, +8 pad
  const int tid = threadIdx.x;
  const int wid = tid >> 6, lane = tid & 63, quad = lane >> 4, r16 = lane & 15;
  const int x   = blockIdx.x;
  const int pair = x >> 5, hl = x & 31;
  const int b = hl >> 4, h = hl & 15, hk = h >> 2;

  const __bf16* kbase = k  + (size_t)(b * KVH_ + hk) * T_ * HD_;
  const __bf16* vbase = vT + (size_t)(b * KVH_ + hk) * HD_ * T_;
  __bf16* Pw = Ps[wid];
  const float sc = 0.08838834764831845f;  // 1/sqrt(128)
  const float NEG = -__builtin_inff();
  bf16x8 ones;
  #pragma unroll
  for (int i = 0; i < 8; i++) ones[i] = (__bf16)1.0f;

  #pragma unroll 1
  for (int seg = 0; seg < 2; ++seg) {
    const int qt = seg ? pair : (15 - pair);
    const int nt = 2 * (qt + 1);
    const int r0 = qt * 128 + wid * 16;   // this wave's 16 q-rows

    const __bf16* qrow = q + ((size_t)(b * NH_ + h) * T_ + r0 + r16) * HD_;
    bf16x8 qf[4];
    #pragma unroll
    for (int kb = 0; kb < 4; kb++) qf[kb] = *(const bf16x8*)&qrow[kb * 32 + quad * 8];

    floatx4 o[8], ol = (floatx4){0.f, 0.f, 0.f, 0.f};
    #pragma unroll
    for (int j = 0; j < 8; j++) o[j] = (floatx4){0.f, 0.f, 0.f, 0.f};
    float m_r[4] = {NEG, NEG, NEG, NEG};

    bf16x8 kreg[2], vreg[2];
    kv_prefetch8(kbase, vbase, 0, wid, lane, kreg, vreg);

    #pragma unroll 1
    for (int it = 0; it < nt; ++it) {
      __syncthreads();                      // all waves done reading previous tile
      kv_commit8(Ks, Vs, wid, lane, kreg, vreg);
      __syncthreads();                      // tile it visible
      if (it + 1 < nt) kv_prefetch8(kbase, vbase, (it + 1) * 64, wid, lane, kreg, vreg);

      const int kt0 = it * 64;
      if (kt0 <= r0 + 15) {                 // wave-uniform causal skip (no barriers inside)
        floatx4 s[4];
        #pragma unroll
        for (int cb = 0; cb < 4; cb++) s[cb] = (floatx4){0.f, 0.f, 0.f, 0.f};
        #pragma unroll
        for (int kb = 0; kb < 4; kb++)
          #pragma unroll
          for (int cb = 0; cb < 4; cb++) {
            bf16x8 kf = *(const bf16x8*)&Ks[(cb * 4 + kb) * 512 + r16 * 32 + quad * 8];
            s[cb] = __builtin_amdgcn_mfma_f32_16x16x32_bf16(qf[kb], kf, s[cb], 0, 0, 0);
          }

        const bool needmask = (kt0 + 63 > r0);  // wave-uniform
        float alpha[4];
        #pragma unroll
        for (int reg = 0; reg < 4; reg++) {
          const int rowq = r0 + quad * 4 + reg;
          float v0 = s[0][reg] * sc, v1 = s[1][reg] * sc;
          float v2 = s[2][reg] * sc, v3 = s[3][reg] * sc;
          if (needmask) {
            if (kt0 +      r16 > rowq) v0 = NEG;
            if (kt0 + 16 + r16 > rowq) v1 = NEG;
            if (kt0 + 32 + r16 > rowq) v2 = NEG;
            if (kt0 + 48 + r16 > rowq) v3 = NEG;
          }
          float mx = fmaxf(fmaxf(v0, v1), fmaxf(v2, v3));
          #pragma unroll
          for (int off = 8; off; off >>= 1) mx = fmaxf(mx, __shfl_xor(mx, off));
          float mnew = fmaxf(m_r[reg], mx);
          alpha[reg] = __expf(m_r[reg] - mnew);
          m_r[reg] = mnew;
          Pw[(quad * 4 + reg) * 72 +      r16] = (__bf16)__expf(v0 - mnew);
          Pw[(quad * 4 + reg) * 72 + 16 + r16] = (__bf16)__expf(v1 - mnew);
          Pw[(quad * 4 + reg) * 72 + 32 + r16] = (__bf16)__expf(v2 - mnew);
          Pw[(quad * 4 + reg) * 72 + 48 + r16] = (__bf16)__expf(v3 - mnew);
        }
        #pragma unroll
        for (int reg = 0; reg < 4; reg++) {
          ol[reg] *= alpha[reg];
          #pragma unroll
          for (int j = 0; j < 8; j++) o[j][reg] *= alpha[reg];
        }
        __asm__ volatile("" ::: "memory");  // wave-private P: writes before reads
        bf16x8 pf0 = *(const bf16x8*)&Pw[r16 * 72 + quad * 8];
        bf16x8 pf1 = *(const bf16x8*)&Pw[r16 * 72 + 32 + quad * 8];
        ol = __builtin_amdgcn_mfma_f32_16x16x32_bf16(pf0, ones, ol, 0, 0, 0);
        ol = __builtin_amdgcn_mfma_f32_16x16x32_bf16(pf1, ones, ol, 0, 0, 0);
        #pragma unroll
        for (int j = 0; j < 8; j++) {
          bf16x8 vf0 = *(const bf16x8*)&Vs[(j * 2 + 0) * 512 + r16 * 32 + quad * 8];
          bf16x8 vf1 = *(const bf16x8*)&Vs[(j * 2 + 1) * 512 + r16 * 32 + quad * 8];
          o[j] = __builtin_amdgcn_mfma_f32_16x16x32_bf16(pf0, vf0, o[j], 0, 0, 0);
          o[j] = __builtin_amdgcn_mfma_f32_16x16x32_bf16(pf1, vf1, o[j], 0, 0, 0);
        }
      }
    }

    #pragma unroll
    for (int reg = 0; reg < 4; reg++) {
      int trow = r0 + quad * 4 + reg;
      float inv = 1.0f / ol[reg];  // rowsum identical across lanes (ones-MFMA trick)
      __bf16* yr = y + ((size_t)(b * T_) + trow) * C_ + h * HD_;
      #pragma unroll
      for (int j = 0; j < 8; j++) yr[j * 16 + r16] = (__bf16)(o[j][reg] * inv);
    }
  }
}

extern "C" void kernel_launch(void* const* d_in, const int* in_sizes, int n_in,
                              void* d_out, int out_size, void* d_ws, size_t ws_size,
                              hipStream_t stream) {
  const float* x     = (const float*)d_in[0];
  const float* wqkv  = (const float*)d_in[1];
  const float* wproj = (const float*)d_in[2];
  const float* qw    = (const float*)d_in[3];
  const float* kw    = (const float*)d_in[4];
  const float* fc    = (const float*)d_in[5];
  const float* fs    = (const float*)d_in[6];
  float* out = (float*)d_out;

  char* w = (char*)d_ws;
  __bf16* xb     = (__bf16*)w; w += (size_t)M_ * C_ * 2;
  __bf16* wqkvb  = (__bf16*)w; w += (size_t)QKV_ * C_ * 2;
  __bf16* wprojb = (__bf16*)w; w += (size_t)C_ * C_ * 2;
  __bf16* qkv    = (__bf16*)w; w += (size_t)M_ * QKV_ * 2;
  __bf16* qn     = (__bf16*)w; w += (size_t)B_ * NH_ * T_ * HD_ * 2;
  __bf16* kn     = (__bf16*)w; w += (size_t)B_ * KVH_ * T_ * HD_ * 2;
  __bf16* vT     = (__bf16*)w; w += (size_t)B_ * KVH_ * T_ * HD_ * 2;
  __bf16* ybf    = (__bf16*)w; w += (size_t)M_ * C_ * 2;

  const int n0 = M_ * C_ / 4, n1 = QKV_ * C_ / 4, n2 = C_ * C_ / 4;
  cvt3<<<(n0 + n1 + n2 + 255) / 256, 256, 0, stream>>>(x, xb, n0, wqkv, wqkvb, n1, wproj, wprojb, n2);

  gemm_bt<__bf16><<<dim3(QKV_ / 128, M_ / 128), 256, 0, stream>>>(xb, wqkvb, qkv, QKV_, C_);
  rope_norm<<<M_ / 4, 256, 0, stream>>>(qkv, qw, kw, fc, fs, qn, kn);
  vtrans<<<dim3(T_ / 64, HD_ / 64, B_ * KVH_), 256, 0, stream>>>(qkv, vT);
  flash<<<dim3(256), 512, 0, stream>>>(qn, kn, vT, ybf);
  gemm_bt<float><<<dim3(C_ / 128, M_ / 128), 256, 0, stream>>>(ybf, wprojb, out, C_, C_);
}